// Round 1
// baseline (1072.146 us; speedup 1.0000x reference)
//
#include <hip/hip_runtime.h>
#include <hip/hip_bf16.h>
#include <math.h>

#define H 256
#define EPSV 1e-6f

typedef __attribute__((ext_vector_type(8))) short bf16x8;
typedef __attribute__((ext_vector_type(4))) float f32x4;

static __device__ __forceinline__ unsigned short f2bf(float x){
  union { float f; unsigned u; } v; v.f = x;
  unsigned r = v.u + 0x7FFF + ((v.u >> 16) & 1);
  return (unsigned short)(r >> 16);
}

// ---------- counting sort by case ----------
__global__ void count_kernel(const int* __restrict__ cidx, int* __restrict__ counts, int E){
  int e = blockIdx.x * blockDim.x + threadIdx.x;
  if (e < E) atomicAdd(&counts[cidx[e]], 1);
}

__global__ __launch_bounds__(1024) void scan_offsets(const int* __restrict__ counts,
                                                     int* __restrict__ offsets, int n){
  __shared__ int a[1024];
  int tid = threadIdx.x;
  int per = (n + 1023) >> 10;
  int start = tid * per;
  int end = min(start + per, n);
  int s = 0;
  for (int i = start; i < end; ++i) s += counts[i];
  a[tid] = s;
  __syncthreads();
  for (int d = 1; d < 1024; d <<= 1){
    int v = 0;
    if (tid >= d) v = a[tid - d];
    __syncthreads();
    if (tid >= d) a[tid] += v;
    __syncthreads();
  }
  int run = a[tid] - s;           // exclusive prefix
  for (int i = start; i < end; ++i){ offsets[i] = run; run += counts[i]; }
  if (tid == 1023) offsets[n] = a[1023];
}

__global__ void fill_kernel(const int* __restrict__ cidx, int* __restrict__ cursor,
                            const int* __restrict__ offs, int* __restrict__ elist, int E){
  int e = blockIdx.x * blockDim.x + threadIdx.x;
  if (e < E){
    int c = cidx[e];
    int pos = atomicAdd(&cursor[c], 1);
    elist[offs[c] + pos] = e;
  }
}

// deterministic order: sort each case's edge list ascending
__global__ void sort_lists(int* __restrict__ elist, const int* __restrict__ offs, int nc){
  int c = blockIdx.x * blockDim.x + threadIdx.x;
  if (c >= nc) return;
  int s = offs[c], e = offs[c + 1];
  for (int i = s + 1; i < e; ++i){
    int v = elist[i];
    int j = i - 1;
    while (j >= s && elist[j] > v){ elist[j + 1] = elist[j]; --j; }
    elist[j + 1] = v;
  }
}

// ---------- W1 (1024x256 f32) -> W1T bf16 (256x1024) ----------
__global__ void w1_convert(const float* __restrict__ W1, unsigned short* __restrict__ w1t){
  int t = blockIdx.x * blockDim.x + threadIdx.x;   // t = n*1024 + k
  int n = t >> 10, k = t & 1023;
  w1t[t] = f2bf(W1[k * H + n]);
}

// ---------- per-case deg and sum ----------
__global__ __launch_bounds__(256) void case_sums(const float* __restrict__ er,
                                                 const float* __restrict__ ew,
                                                 const int* __restrict__ elist,
                                                 const int* __restrict__ offs,
                                                 float* __restrict__ csum,
                                                 float* __restrict__ cdeg){
  int c = blockIdx.x, tid = threadIdx.x;
  int s = offs[c], e = offs[c + 1];
  float acc = 0.f;
  for (int i = s; i < e; ++i){
    int ed = elist[i];
    acc += er[(size_t)ed * H + tid] * ew[ed];
  }
  csum[(size_t)c * H + tid] = acc;
  if (tid == 0){
    float d = 0.f;
    for (int i = s; i < e; ++i) d += ew[elist[i]];
    cdeg[c] = d;
  }
}

// ---------- fused feat-build + MLP (bf16 MFMA) -> logits ----------
__global__ __launch_bounds__(256) void fused_mlp(
    const float* __restrict__ er, const float* __restrict__ ew,
    const int* __restrict__ cidx, const float* __restrict__ cdeg,
    const float* __restrict__ csum, const unsigned short* __restrict__ w1t,
    const float* __restrict__ b1, const float* __restrict__ w2,
    const float* __restrict__ b2, float* __restrict__ logits, int E)
{
  __shared__ unsigned short feat[32 * 1024];   // 64 KB, XOR-swizzled rows
  __shared__ float lpart[32];
  int tid = threadIdx.x;
  int e0 = blockIdx.x * 32;

  if (tid < 32) lpart[tid] = 0.f;

  // Phase A: build feat rows (32 edges x 1024 bf16)
  for (int m = 0; m < 32; ++m){
    int e = e0 + m;
    unsigned swz = (unsigned)((m & 7) << 3);
    unsigned base = (unsigned)m * 1024u;
    int h = tid;
    if (e < E){
      int c = cidx[e];                 // uniform -> scalar loads
      float w = ew[e];
      float deg = cdeg[c];
      float x = er[(size_t)e * H + h];
      float s = csum[(size_t)c * H + h];
      float rem = deg - w;
      float ctx;
      if (rem <= EPSV) ctx = s / fmaxf(deg, EPSV);
      else             ctx = (s - x * w) / fmaxf(rem, 1e-8f);
      feat[base + ((unsigned)(h      ) ^ swz)] = f2bf(x);
      feat[base + ((unsigned)(h + 256) ^ swz)] = f2bf(ctx);
      feat[base + ((unsigned)(h + 512) ^ swz)] = f2bf(x * ctx);
      feat[base + ((unsigned)(h + 768) ^ swz)] = f2bf(fabsf(x - ctx));
    } else {
      feat[base + ((unsigned)(h      ) ^ swz)] = 0;
      feat[base + ((unsigned)(h + 256) ^ swz)] = 0;
      feat[base + ((unsigned)(h + 512) ^ swz)] = 0;
      feat[base + ((unsigned)(h + 768) ^ swz)] = 0;
    }
  }
  __syncthreads();

  // Phase B: 4 waves; wave w owns cols [64w, 64w+64), rows 0..31
  int wv = tid >> 6, lane = tid & 63;
  int l15 = lane & 15, lg = lane >> 4;
  int colb = wv * 64;

  f32x4 acc[2][4];
  #pragma unroll
  for (int mt = 0; mt < 2; ++mt)
    #pragma unroll
    for (int nt = 0; nt < 4; ++nt) acc[mt][nt] = (f32x4){0.f, 0.f, 0.f, 0.f};

  for (int ks = 0; ks < 32; ++ks){
    int kk = ks * 32 + lg * 8;
    bf16x8 a[2], b[4];
    #pragma unroll
    for (int mt = 0; mt < 2; ++mt){
      int row = mt * 16 + l15;
      a[mt] = *(const bf16x8*)&feat[(unsigned)row * 1024u + ((unsigned)kk ^ (unsigned)((row & 7) << 3))];
    }
    #pragma unroll
    for (int nt = 0; nt < 4; ++nt){
      int col = colb + nt * 16 + l15;
      b[nt] = *(const bf16x8*)&w1t[(size_t)col * 1024 + kk];
    }
    #pragma unroll
    for (int mt = 0; mt < 2; ++mt)
      #pragma unroll
      for (int nt = 0; nt < 4; ++nt)
        acc[mt][nt] = __builtin_amdgcn_mfma_f32_16x16x32_bf16(a[mt], b[nt], acc[mt][nt], 0, 0, 0);
  }

  // epilogue: relu(h + b1) dot W2, reduce over cols
  float p[2][4] = {{0.f,0.f,0.f,0.f},{0.f,0.f,0.f,0.f}};
  #pragma unroll
  for (int nt = 0; nt < 4; ++nt){
    int col = colb + nt * 16 + l15;
    float b1c = b1[col], w2c = w2[col];
    #pragma unroll
    for (int mt = 0; mt < 2; ++mt)
      #pragma unroll
      for (int j = 0; j < 4; ++j){
        float v = acc[mt][nt][j] + b1c;
        v = fmaxf(v, 0.f);
        p[mt][j] += v * w2c;
      }
  }
  #pragma unroll
  for (int mask = 1; mask < 16; mask <<= 1)
    #pragma unroll
    for (int mt = 0; mt < 2; ++mt)
      #pragma unroll
      for (int j = 0; j < 4; ++j)
        p[mt][j] += __shfl_xor(p[mt][j], mask);

  if (l15 == 0){
    #pragma unroll
    for (int mt = 0; mt < 2; ++mt)
      #pragma unroll
      for (int j = 0; j < 4; ++j)
        atomicAdd(&lpart[mt * 16 + lg * 4 + j], p[mt][j]);
  }
  __syncthreads();
  if (tid < 32 && e0 + tid < E)
    logits[e0 + tid] = lpart[tid] + b2[0];
}

// ---------- per-case softmax + final weighted aggregation ----------
__global__ __launch_bounds__(256) void finalize(
    const float* __restrict__ er, const float* __restrict__ ew,
    const float* __restrict__ logits, const int* __restrict__ elist,
    const int* __restrict__ offs, const float* __restrict__ cdeg,
    float* __restrict__ out)
{
  int c = blockIdx.x, tid = threadIdx.x;
  int s = offs[c], e = offs[c + 1];
  int n = e - s;
  if (n == 0){ out[(size_t)c * H + tid] = 0.f; return; }

  __shared__ float red[256];
  __shared__ float fa[1024];

  float m = -INFINITY;
  for (int i = tid; i < n; i += 256) m = fmaxf(m, logits[elist[s + i]]);
  red[tid] = m; __syncthreads();
  for (int d = 128; d > 0; d >>= 1){
    if (tid < d) red[tid] = fmaxf(red[tid], red[tid + d]);
    __syncthreads();
  }
  float gmax = red[0]; __syncthreads();

  float sm = 0.f;
  for (int i = tid; i < n; i += 256) sm += expf(logits[elist[s + i]] - gmax);
  red[tid] = sm; __syncthreads();
  for (int d = 128; d > 0; d >>= 1){
    if (tid < d) red[tid] += red[tid + d];
    __syncthreads();
  }
  float gsum = red[0];
  float degc = cdeg[c];

  float acc = 0.f;
  for (int base = 0; base < n; base += 1024){
    int chunk = min(n - base, 1024);
    __syncthreads();
    for (int i = tid; i < chunk; i += 256){
      int ed = elist[s + base + i];
      float al = expf(logits[ed] - gmax) / (gsum + 1e-8f);
      fa[i] = 0.8f * al + 0.2f * ew[ed] / (degc + 1e-8f);
    }
    __syncthreads();
    for (int i = 0; i < chunk; ++i)
      acc += fa[i] * er[(size_t)elist[s + base + i] * H + tid];
  }
  out[(size_t)c * H + tid] = acc;
}

extern "C" void kernel_launch(void* const* d_in, const int* in_sizes, int n_in,
                              void* d_out, int out_size, void* d_ws, size_t ws_size,
                              hipStream_t stream){
  const float* er  = (const float*)d_in[0];
  const float* ew  = (const float*)d_in[1];
  const int*   cid = (const int*)d_in[2];
  const float* W1  = (const float*)d_in[4];
  const float* b1  = (const float*)d_in[5];
  const float* W2  = (const float*)d_in[6];
  const float* b2  = (const float*)d_in[7];
  float* out = (float*)d_out;

  int E  = in_sizes[1];
  int NC = out_size / H;

  char* ws = (char*)d_ws;
  auto al = [](size_t x){ return (x + 255) & ~(size_t)255; };
  size_t o = 0;
  int* counts = (int*)(ws + o);  o = al(o + (size_t)NC * 4);
  int* cursor = (int*)(ws + o);  o = al(o + (size_t)NC * 4);
  int* offs   = (int*)(ws + o);  o = al(o + (size_t)(NC + 1) * 4);
  int* elist  = (int*)(ws + o);  o = al(o + (size_t)E * 4);
  float* cdeg = (float*)(ws + o); o = al(o + (size_t)NC * 4);
  float* csum = (float*)(ws + o); o = al(o + (size_t)NC * H * 4);
  float* logits = (float*)(ws + o); o = al(o + (size_t)E * 4);
  unsigned short* w1t = (unsigned short*)(ws + o); o = al(o + (size_t)1024 * H * 2);

  hipMemsetAsync(counts, 0, (size_t)NC * 4, stream);
  hipMemsetAsync(cursor, 0, (size_t)NC * 4, stream);

  count_kernel<<<(E + 255) / 256, 256, 0, stream>>>(cid, counts, E);
  scan_offsets<<<1, 1024, 0, stream>>>(counts, offs, NC);
  fill_kernel<<<(E + 255) / 256, 256, 0, stream>>>(cid, cursor, offs, elist, E);
  sort_lists<<<(NC + 255) / 256, 256, 0, stream>>>(elist, offs, NC);
  w1_convert<<<(1024 * H) / 256, 256, 0, stream>>>(W1, w1t);
  case_sums<<<NC, 256, 0, stream>>>(er, ew, elist, offs, csum, cdeg);
  fused_mlp<<<(E + 31) / 32, 256, 0, stream>>>(er, ew, cid, cdeg, csum, w1t, b1, W2, b2, logits, E);
  finalize<<<NC, 256, 0, stream>>>(er, ew, logits, elist, offs, cdeg, out);
}

// Round 2
// 695.531 us; speedup vs baseline: 1.5415x; 1.5415x over previous
//
#include <hip/hip_runtime.h>
#include <hip/hip_bf16.h>
#include <math.h>

#define H 256
#define EPSV 1e-6f

typedef __attribute__((ext_vector_type(8))) short bf16x8;
typedef __attribute__((ext_vector_type(4))) float f32x4;

static __device__ __forceinline__ unsigned short f2bf(float x){
  union { float f; unsigned u; } v; v.f = x;
  unsigned r = v.u + 0x7FFF + ((v.u >> 16) & 1);
  return (unsigned short)(r >> 16);
}

// ---------- counting sort by case ----------
__global__ void count_kernel(const int* __restrict__ cidx, int* __restrict__ counts, int E){
  int e = blockIdx.x * blockDim.x + threadIdx.x;
  if (e < E) atomicAdd(&counts[cidx[e]], 1);
}

__global__ __launch_bounds__(1024) void scan_offsets(const int* __restrict__ counts,
                                                     int* __restrict__ offsets, int n){
  __shared__ int a[1024];
  int tid = threadIdx.x;
  int per = (n + 1023) >> 10;
  int start = tid * per;
  int end = min(start + per, n);
  int s = 0;
  for (int i = start; i < end; ++i) s += counts[i];
  a[tid] = s;
  __syncthreads();
  for (int d = 1; d < 1024; d <<= 1){
    int v = 0;
    if (tid >= d) v = a[tid - d];
    __syncthreads();
    if (tid >= d) a[tid] += v;
    __syncthreads();
  }
  int run = a[tid] - s;           // exclusive prefix
  for (int i = start; i < end; ++i){ offsets[i] = run; run += counts[i]; }
  if (tid == 1023) offsets[n] = a[1023];
}

__global__ void fill_kernel(const int* __restrict__ cidx, int* __restrict__ cursor,
                            const int* __restrict__ offs, int* __restrict__ elist, int E){
  int e = blockIdx.x * blockDim.x + threadIdx.x;
  if (e < E){
    int c = cidx[e];
    int pos = atomicAdd(&cursor[c], 1);
    elist[offs[c] + pos] = e;
  }
}

// deterministic order: sort each case's edge list ascending
__global__ void sort_lists(int* __restrict__ elist, const int* __restrict__ offs, int nc){
  int c = blockIdx.x * blockDim.x + threadIdx.x;
  if (c >= nc) return;
  int s = offs[c], e = offs[c + 1];
  for (int i = s + 1; i < e; ++i){
    int v = elist[i];
    int j = i - 1;
    while (j >= s && elist[j] > v){ elist[j + 1] = elist[j]; --j; }
    elist[j + 1] = v;
  }
}

// ---------- W1 (1024x256 f32, row=k, col=n) -> tiled bf16 [k/32][col][k%32] ----------
__global__ void w1_convert(const float* __restrict__ W1, unsigned short* __restrict__ w1t2){
  int t = blockIdx.x * blockDim.x + threadIdx.x;   // 262144 threads, reads contiguous
  int k = t >> 8, n = t & 255;
  w1t2[((size_t)(k >> 5) * 256 + n) * 32 + (k & 31)] = f2bf(W1[t]);
}

// ---------- per-case deg and sum ----------
__global__ __launch_bounds__(256) void case_sums(const float* __restrict__ er,
                                                 const float* __restrict__ ew,
                                                 const int* __restrict__ elist,
                                                 const int* __restrict__ offs,
                                                 float* __restrict__ csum,
                                                 float* __restrict__ cdeg){
  int c = blockIdx.x, tid = threadIdx.x;
  int s = offs[c], e = offs[c + 1];
  float acc = 0.f;
  for (int i = s; i < e; ++i){
    int ed = elist[i];
    acc += er[(size_t)ed * H + tid] * ew[ed];
  }
  csum[(size_t)c * H + tid] = acc;
  if (tid == 0){
    float d = 0.f;
    for (int i = s; i < e; ++i) d += ew[elist[i]];
    cdeg[c] = d;
  }
}

// ---------- fused feat-build + MLP (bf16 MFMA) -> logits ----------
__global__ __launch_bounds__(256, 2) void fused_mlp(
    const float* __restrict__ er, const float* __restrict__ ew,
    const int* __restrict__ cidx, const float* __restrict__ cdeg,
    const float* __restrict__ csum, const unsigned short* __restrict__ w1t2,
    const float* __restrict__ b1, const float* __restrict__ w2,
    const float* __restrict__ b2, float* __restrict__ logits, int E)
{
  __shared__ unsigned short feat[32 * 1024];   // 64 KB, XOR-swizzled (16B-unit) rows
  __shared__ float lpart[4][32];
  int tid = threadIdx.x;
  int e0 = blockIdx.x * 32;

  // ---- Phase A: 8 threads/row, all loads batched ----
  {
    int r  = tid >> 3;         // row 0..31
    int q  = tid & 7;          // col octant (32 cols each)
    int e  = e0 + r;
    int c0 = q * 32;
    bool valid = (e < E);
    int   c   = valid ? cidx[e] : 0;
    float w   = valid ? ew[e]   : 0.f;
    float deg = valid ? cdeg[c] : 1.f;
    float rem = deg - w;
    bool  fb  = (rem <= EPSV);
    float inv = fb ? (1.0f / fmaxf(deg, EPSV)) : (1.0f / fmaxf(rem, 1e-8f));

    const float* erow = er   + (size_t)e * H + c0;
    const float* srow = csum + (size_t)c * H + c0;
    f32x4 xr[8], sr[8];
    if (valid){
      #pragma unroll
      for (int j = 0; j < 8; ++j) xr[j] = *(const f32x4*)(erow + 4 * j);
      #pragma unroll
      for (int j = 0; j < 8; ++j) sr[j] = *(const f32x4*)(srow + 4 * j);
    } else {
      #pragma unroll
      for (int j = 0; j < 8; ++j){ xr[j] = (f32x4){0,0,0,0}; sr[j] = (f32x4){0,0,0,0}; }
    }

    unsigned swz  = ((unsigned)(r & 7)) << 3;   // XOR on element bits 3..5 (16B units)
    unsigned rowb = (unsigned)r * 1024u;
    #pragma unroll
    for (int j = 0; j < 8; ++j){
      unsigned short fx[4], fc[4], fp[4], fd[4];
      #pragma unroll
      for (int i2 = 0; i2 < 4; ++i2){
        float x = xr[j][i2], s = sr[j][i2];
        float ctx = fb ? (s * inv) : ((s - x * w) * inv);
        fx[i2] = f2bf(x);
        fc[i2] = f2bf(ctx);
        fp[i2] = f2bf(x * ctx);
        fd[i2] = f2bf(fabsf(x - ctx));
      }
      unsigned cc = (unsigned)(c0 + 4 * j);
      uint2 px = { (unsigned)fx[0] | ((unsigned)fx[1] << 16), (unsigned)fx[2] | ((unsigned)fx[3] << 16) };
      uint2 pc = { (unsigned)fc[0] | ((unsigned)fc[1] << 16), (unsigned)fc[2] | ((unsigned)fc[3] << 16) };
      uint2 pp = { (unsigned)fp[0] | ((unsigned)fp[1] << 16), (unsigned)fp[2] | ((unsigned)fp[3] << 16) };
      uint2 pd = { (unsigned)fd[0] | ((unsigned)fd[1] << 16), (unsigned)fd[2] | ((unsigned)fd[3] << 16) };
      *(uint2*)&feat[rowb + ((cc          ) ^ swz)] = px;
      *(uint2*)&feat[rowb + ((cc + 256u   ) ^ swz)] = pc;
      *(uint2*)&feat[rowb + ((cc + 512u   ) ^ swz)] = pp;
      *(uint2*)&feat[rowb + ((cc + 768u   ) ^ swz)] = pd;
    }
  }
  __syncthreads();

  // ---- Phase B: 4 waves split N; dbuf-prefetched B frags ----
  int wv = tid >> 6, lane = tid & 63;
  int l15 = lane & 15, lg = lane >> 4;
  int colb = wv * 64;

  f32x4 acc[2][4];
  #pragma unroll
  for (int mt = 0; mt < 2; ++mt)
    #pragma unroll
    for (int nt = 0; nt < 4; ++nt) acc[mt][nt] = (f32x4){0.f, 0.f, 0.f, 0.f};

  const unsigned short* bp[4];
  #pragma unroll
  for (int nt = 0; nt < 4; ++nt){
    int col = colb + nt * 16 + l15;
    bp[nt] = w1t2 + (size_t)col * 32 + lg * 8;
  }
  // kgrp = seg*8 + ksp; element stride per kgrp = 256*32 = 8192
  bf16x8 bb[2][16];
  #pragma unroll
  for (int seg = 0; seg < 4; ++seg)
    #pragma unroll
    for (int nt = 0; nt < 4; ++nt)
      bb[0][seg * 4 + nt] = *(const bf16x8*)(bp[nt] + (size_t)(seg * 8) * 8192);

  #pragma unroll
  for (int ksp = 0; ksp < 8; ++ksp){
    const int cur = ksp & 1;
    if (ksp < 7){
      #pragma unroll
      for (int seg = 0; seg < 4; ++seg)
        #pragma unroll
        for (int nt = 0; nt < 4; ++nt)
          bb[cur ^ 1][seg * 4 + nt] = *(const bf16x8*)(bp[nt] + (size_t)(seg * 8 + ksp + 1) * 8192);
    }
    #pragma unroll
    for (int seg = 0; seg < 4; ++seg){
      unsigned elem = (unsigned)(seg * 256 + ksp * 32 + lg * 8);
      bf16x8 a[2];
      #pragma unroll
      for (int mt = 0; mt < 2; ++mt){
        unsigned row = (unsigned)(mt * 16 + l15);
        a[mt] = *(const bf16x8*)&feat[row * 1024u + (elem ^ ((row & 7u) << 3))];
      }
      #pragma unroll
      for (int mt = 0; mt < 2; ++mt)
        #pragma unroll
        for (int nt = 0; nt < 4; ++nt)
          acc[mt][nt] = __builtin_amdgcn_mfma_f32_16x16x32_bf16(a[mt], bb[cur][seg * 4 + nt], acc[mt][nt], 0, 0, 0);
    }
  }

  // ---- epilogue: relu(h+b1) dot W2, reduce, deterministic cross-wave sum ----
  float p[2][4] = {{0.f,0.f,0.f,0.f},{0.f,0.f,0.f,0.f}};
  #pragma unroll
  for (int nt = 0; nt < 4; ++nt){
    int col = colb + nt * 16 + l15;
    float b1c = b1[col], w2c = w2[col];
    #pragma unroll
    for (int mt = 0; mt < 2; ++mt)
      #pragma unroll
      for (int j = 0; j < 4; ++j){
        float v = acc[mt][nt][j] + b1c;
        v = fmaxf(v, 0.f);
        p[mt][j] += v * w2c;
      }
  }
  #pragma unroll
  for (int mask = 1; mask < 16; mask <<= 1)
    #pragma unroll
    for (int mt = 0; mt < 2; ++mt)
      #pragma unroll
      for (int j = 0; j < 4; ++j)
        p[mt][j] += __shfl_xor(p[mt][j], mask);

  if (l15 == 0){
    #pragma unroll
    for (int mt = 0; mt < 2; ++mt)
      #pragma unroll
      for (int j = 0; j < 4; ++j)
        lpart[wv][mt * 16 + lg * 4 + j] = p[mt][j];
  }
  __syncthreads();
  if (tid < 32 && e0 + tid < E)
    logits[e0 + tid] = lpart[0][tid] + lpart[1][tid] + lpart[2][tid] + lpart[3][tid] + b2[0];
}

// ---------- per-case softmax + final weighted aggregation ----------
__global__ __launch_bounds__(256) void finalize(
    const float* __restrict__ er, const float* __restrict__ ew,
    const float* __restrict__ logits, const int* __restrict__ elist,
    const int* __restrict__ offs, const float* __restrict__ cdeg,
    float* __restrict__ out)
{
  int c = blockIdx.x, tid = threadIdx.x;
  int s = offs[c], e = offs[c + 1];
  int n = e - s;
  if (n == 0){ out[(size_t)c * H + tid] = 0.f; return; }

  __shared__ float red[256];
  __shared__ float fa[1024];

  float m = -INFINITY;
  for (int i = tid; i < n; i += 256) m = fmaxf(m, logits[elist[s + i]]);
  red[tid] = m; __syncthreads();
  for (int d = 128; d > 0; d >>= 1){
    if (tid < d) red[tid] = fmaxf(red[tid], red[tid + d]);
    __syncthreads();
  }
  float gmax = red[0]; __syncthreads();

  float sm = 0.f;
  for (int i = tid; i < n; i += 256) sm += expf(logits[elist[s + i]] - gmax);
  red[tid] = sm; __syncthreads();
  for (int d = 128; d > 0; d >>= 1){
    if (tid < d) red[tid] += red[tid + d];
    __syncthreads();
  }
  float gsum = red[0];
  float degc = cdeg[c];

  float acc = 0.f;
  for (int base = 0; base < n; base += 1024){
    int chunk = min(n - base, 1024);
    __syncthreads();
    for (int i = tid; i < chunk; i += 256){
      int ed = elist[s + base + i];
      float al = expf(logits[ed] - gmax) / (gsum + 1e-8f);
      fa[i] = 0.8f * al + 0.2f * ew[ed] / (degc + 1e-8f);
    }
    __syncthreads();
    for (int i = 0; i < chunk; ++i)
      acc += fa[i] * er[(size_t)elist[s + base + i] * H + tid];
  }
  out[(size_t)c * H + tid] = acc;
}

extern "C" void kernel_launch(void* const* d_in, const int* in_sizes, int n_in,
                              void* d_out, int out_size, void* d_ws, size_t ws_size,
                              hipStream_t stream){
  const float* er  = (const float*)d_in[0];
  const float* ew  = (const float*)d_in[1];
  const int*   cid = (const int*)d_in[2];
  const float* W1  = (const float*)d_in[4];
  const float* b1  = (const float*)d_in[5];
  const float* W2  = (const float*)d_in[6];
  const float* b2  = (const float*)d_in[7];
  float* out = (float*)d_out;

  int E  = in_sizes[1];
  int NC = out_size / H;

  char* ws = (char*)d_ws;
  auto al = [](size_t x){ return (x + 255) & ~(size_t)255; };
  size_t o = 0;
  int* counts = (int*)(ws + o);  o = al(o + (size_t)NC * 4);
  int* cursor = (int*)(ws + o);  o = al(o + (size_t)NC * 4);
  int* offs   = (int*)(ws + o);  o = al(o + (size_t)(NC + 1) * 4);
  int* elist  = (int*)(ws + o);  o = al(o + (size_t)E * 4);
  float* cdeg = (float*)(ws + o); o = al(o + (size_t)NC * 4);
  float* csum = (float*)(ws + o); o = al(o + (size_t)NC * H * 4);
  float* logits = (float*)(ws + o); o = al(o + (size_t)E * 4);
  unsigned short* w1t2 = (unsigned short*)(ws + o); o = al(o + (size_t)1024 * H * 2);

  hipMemsetAsync(counts, 0, (size_t)NC * 4, stream);
  hipMemsetAsync(cursor, 0, (size_t)NC * 4, stream);

  count_kernel<<<(E + 255) / 256, 256, 0, stream>>>(cid, counts, E);
  scan_offsets<<<1, 1024, 0, stream>>>(counts, offs, NC);
  fill_kernel<<<(E + 255) / 256, 256, 0, stream>>>(cid, cursor, offs, elist, E);
  sort_lists<<<(NC + 255) / 256, 256, 0, stream>>>(elist, offs, NC);
  w1_convert<<<(1024 * H) / 256, 256, 0, stream>>>(W1, w1t2);
  case_sums<<<NC, 256, 0, stream>>>(er, ew, elist, offs, csum, cdeg);
  fused_mlp<<<(E + 31) / 32, 256, 0, stream>>>(er, ew, cid, cdeg, csum, w1t2, b1, W2, b2, logits, E);
  finalize<<<NC, 256, 0, stream>>>(er, ew, logits, elist, offs, cdeg, out);
}

// Round 3
// 516.818 us; speedup vs baseline: 2.0745x; 1.3458x over previous
//
#include <hip/hip_runtime.h>
#include <hip/hip_bf16.h>
#include <math.h>

#define H 256
#define EPSV 1e-6f

typedef __attribute__((ext_vector_type(8))) short bf16x8;
typedef __attribute__((ext_vector_type(4))) float f32x4;
typedef __attribute__((ext_vector_type(4))) unsigned int uint4v;

static __device__ __forceinline__ unsigned short f2bf(float x){
  union { float f; unsigned u; } v; v.f = x;
  unsigned r = v.u + 0x7FFF + ((v.u >> 16) & 1);
  return (unsigned short)(r >> 16);
}

// truncating pack of two f32 into 2 bf16 (hi|lo)
static __device__ __forceinline__ unsigned pk_trunc(float lo, float hi){
  return (__float_as_uint(hi) & 0xffff0000u) | (__float_as_uint(lo) >> 16);
}

// ---------- counting sort by case ----------
__global__ void count_kernel(const int* __restrict__ cidx, int* __restrict__ counts, int E){
  int e = blockIdx.x * blockDim.x + threadIdx.x;
  if (e < E) atomicAdd(&counts[cidx[e]], 1);
}

__global__ __launch_bounds__(1024) void scan_offsets(const int* __restrict__ counts,
                                                     int* __restrict__ offsets, int n){
  __shared__ int a[1024];
  int tid = threadIdx.x;
  int per = (n + 1023) >> 10;
  int start = tid * per;
  int end = min(start + per, n);
  int s = 0;
  for (int i = start; i < end; ++i) s += counts[i];
  a[tid] = s;
  __syncthreads();
  for (int d = 1; d < 1024; d <<= 1){
    int v = 0;
    if (tid >= d) v = a[tid - d];
    __syncthreads();
    if (tid >= d) a[tid] += v;
    __syncthreads();
  }
  int run = a[tid] - s;
  for (int i = start; i < end; ++i){ offsets[i] = run; run += counts[i]; }
  if (tid == 1023) offsets[n] = a[1023];
}

__global__ void fill_kernel(const int* __restrict__ cidx, int* __restrict__ cursor,
                            const int* __restrict__ offs, int* __restrict__ elist, int E){
  int e = blockIdx.x * blockDim.x + threadIdx.x;
  if (e < E){
    int c = cidx[e];
    int pos = atomicAdd(&cursor[c], 1);
    elist[offs[c] + pos] = e;
  }
}

__global__ void sort_lists(int* __restrict__ elist, const int* __restrict__ offs, int nc){
  int c = blockIdx.x * blockDim.x + threadIdx.x;
  if (c >= nc) return;
  int s = offs[c], e = offs[c + 1];
  for (int i = s + 1; i < e; ++i){
    int v = elist[i];
    int j = i - 1;
    while (j >= s && elist[j] > v){ elist[j + 1] = elist[j]; --j; }
    elist[j + 1] = v;
  }
}

// ---------- W1 (1024x256 f32 row=k,col=n) -> bf16 tiled [k/32][col][k%32] ----------
__global__ void w1_convert(const float* __restrict__ W1, unsigned short* __restrict__ w1t2){
  int t = blockIdx.x * blockDim.x + threadIdx.x;
  int k = t >> 8, n = t & 255;
  w1t2[((size_t)(k >> 5) * 256 + n) * 32 + (k & 31)] = f2bf(W1[t]);
}

// ---------- per-case deg and sum: 1 wave per case, f32x4 columns ----------
__global__ __launch_bounds__(64) void case_sums(const float* __restrict__ er,
                                                const float* __restrict__ ew,
                                                const int* __restrict__ elist,
                                                const int* __restrict__ offs,
                                                float* __restrict__ csum,
                                                float* __restrict__ cdeg){
  int c = blockIdx.x, lane = threadIdx.x;
  int s = offs[c], e = offs[c + 1];
  f32x4 acc = (f32x4){0.f,0.f,0.f,0.f};
  float dacc = 0.f;
  for (int i = s; i < e; ++i){
    int ed = elist[i];
    float w = ew[ed];
    f32x4 v = *(const f32x4*)&er[(size_t)ed * H + lane * 4];
    acc += v * w;
    dacc += w;
  }
  *(f32x4*)&csum[(size_t)c * H + lane * 4] = acc;
  if (lane == 0) cdeg[c] = dacc;
}

// ---------- fused feat-build + MLP (bf16 MFMA) -> logits ----------
// BM=128 edges/block, 512 threads (8 waves as 2M x 4N), x/ctx in LDS,
// seg2 (x*ctx) and seg3 (|x-ctx|) A-frags computed on the fly.
__global__ __launch_bounds__(512, 2) void fused_mlp(
    const float* __restrict__ er, const float* __restrict__ ew,
    const int* __restrict__ cidx, const float* __restrict__ cdeg,
    const float* __restrict__ csum, const unsigned short* __restrict__ w1t2,
    const float* __restrict__ b1, const float* __restrict__ w2,
    const float* __restrict__ b2, float* __restrict__ logits, int E)
{
  __shared__ unsigned short xl[128 * 256];   // 64 KB
  __shared__ unsigned short cl[128 * 256];   // 64 KB
  __shared__ float lpart[4][128];            // 2 KB
  int tid = threadIdx.x;
  long e0 = (long)blockIdx.x * 128;

  // ---- Phase A: build x/ctx LDS tiles. 4 threads per row, 64 cols each ----
  {
    int r = tid >> 2, q = tid & 3;
    long e = e0 + r;
    bool valid = (e < (long)E);
    int   c   = valid ? cidx[e] : 0;
    float w   = valid ? ew[e]   : 0.f;
    float deg = valid ? cdeg[c] : 1.f;
    float rem = deg - w;
    bool  fb  = (rem <= EPSV);
    float inv  = fb ? (1.0f / fmaxf(deg, EPSV)) : (1.0f / fmaxf(rem, 1e-8f));
    float wsel = fb ? 0.f : w;     // ctx = (s - wsel*x) * inv covers both branches

    const float* erow = er   + (size_t)e * H + q * 64;
    const float* srow = csum + (size_t)c * H + q * 64;
    f32x4 xr[16], sr[16];
    if (valid){
      #pragma unroll
      for (int j = 0; j < 16; ++j) xr[j] = *(const f32x4*)(erow + 4 * j);
      #pragma unroll
      for (int j = 0; j < 16; ++j) sr[j] = *(const f32x4*)(srow + 4 * j);
    } else {
      #pragma unroll
      for (int j = 0; j < 16; ++j){ xr[j] = (f32x4){0,0,0,0}; sr[j] = (f32x4){0,0,0,0}; }
    }

    unsigned swz  = ((unsigned)(r & 7)) << 3;
    unsigned rowb = (unsigned)r * 256u;
    #pragma unroll
    for (int j2 = 0; j2 < 8; ++j2){          // 8 chunks of 8 elems
      unsigned xw[4], cw[4];
      #pragma unroll
      for (int d = 0; d < 4; ++d){
        float x0 = xr[2*j2 + (d>>1)][(d&1)*2+0], x1 = xr[2*j2 + (d>>1)][(d&1)*2+1];
        float s0 = sr[2*j2 + (d>>1)][(d&1)*2+0], s1 = sr[2*j2 + (d>>1)][(d&1)*2+1];
        float c0 = (s0 - wsel * x0) * inv;
        float c1 = (s1 - wsel * x1) * inv;
        xw[d] = (unsigned)f2bf(x0) | ((unsigned)f2bf(x1) << 16);
        cw[d] = (unsigned)f2bf(c0) | ((unsigned)f2bf(c1) << 16);
      }
      unsigned elem = (unsigned)(q * 64 + j2 * 8);
      unsigned off  = rowb + (elem ^ swz);
      *(uint4v*)&xl[off] = (uint4v){xw[0], xw[1], xw[2], xw[3]};
      *(uint4v*)&cl[off] = (uint4v){cw[0], cw[1], cw[2], cw[3]};
    }
  }
  __syncthreads();

  // ---- Phase B: 8 waves as (wm 0-1) x (wn 0-3); wave tile 64 rows x 64 cols ----
  int wv = tid >> 6, lane = tid & 63;
  int wm = wv >> 2, wn = wv & 3;
  int l15 = lane & 15, lg = lane >> 4;

  f32x4 acc[4][4];
  #pragma unroll
  for (int mt = 0; mt < 4; ++mt)
    #pragma unroll
    for (int nt = 0; nt < 4; ++nt) acc[mt][nt] = (f32x4){0.f,0.f,0.f,0.f};

  const unsigned short* bp = w1t2 + ((size_t)(wn * 64 + l15)) * 32 + lg * 8;

  #pragma unroll
  for (int ksi = 0; ksi < 8; ++ksi){
    // B-frags for the 4 segments' kgrps at this ksi (issued first -> latency cover)
    bf16x8 bb[4][4];
    #pragma unroll
    for (int sg = 0; sg < 4; ++sg)
      #pragma unroll
      for (int nt = 0; nt < 4; ++nt)
        bb[sg][nt] = *(const bf16x8*)(bp + (size_t)(sg * 8 + ksi) * 8192 + nt * 512);

    unsigned eb = (unsigned)(ksi * 32 + lg * 8);
    bf16x8 xa[4], ca[4], pa[4], da[4];
    #pragma unroll
    for (int mt = 0; mt < 4; ++mt){
      unsigned row = (unsigned)(wm * 64 + mt * 16 + l15);
      unsigned off = row * 256u + (eb ^ ((row & 7u) << 3));
      xa[mt] = *(const bf16x8*)&xl[off];
      ca[mt] = *(const bf16x8*)&cl[off];
      uint4v xu = *(uint4v*)&xa[mt];
      uint4v cu = *(uint4v*)&ca[mt];
      unsigned pw[4], dw[4];
      #pragma unroll
      for (int d = 0; d < 4; ++d){
        float xlo = __uint_as_float(xu[d] << 16);
        float xhi = __uint_as_float(xu[d] & 0xffff0000u);
        float clo = __uint_as_float(cu[d] << 16);
        float chi = __uint_as_float(cu[d] & 0xffff0000u);
        pw[d] = pk_trunc(xlo * clo, xhi * chi);
        dw[d] = pk_trunc(fabsf(xlo - clo), fabsf(xhi - chi));
      }
      uint4v pv = {pw[0], pw[1], pw[2], pw[3]};
      uint4v dv = {dw[0], dw[1], dw[2], dw[3]};
      pa[mt] = *(bf16x8*)&pv;
      da[mt] = *(bf16x8*)&dv;
    }

    #pragma unroll
    for (int mt = 0; mt < 4; ++mt)
      #pragma unroll
      for (int nt = 0; nt < 4; ++nt)
        acc[mt][nt] = __builtin_amdgcn_mfma_f32_16x16x32_bf16(xa[mt], bb[0][nt], acc[mt][nt], 0, 0, 0);
    #pragma unroll
    for (int mt = 0; mt < 4; ++mt)
      #pragma unroll
      for (int nt = 0; nt < 4; ++nt)
        acc[mt][nt] = __builtin_amdgcn_mfma_f32_16x16x32_bf16(ca[mt], bb[1][nt], acc[mt][nt], 0, 0, 0);
    #pragma unroll
    for (int mt = 0; mt < 4; ++mt)
      #pragma unroll
      for (int nt = 0; nt < 4; ++nt)
        acc[mt][nt] = __builtin_amdgcn_mfma_f32_16x16x32_bf16(pa[mt], bb[2][nt], acc[mt][nt], 0, 0, 0);
    #pragma unroll
    for (int mt = 0; mt < 4; ++mt)
      #pragma unroll
      for (int nt = 0; nt < 4; ++nt)
        acc[mt][nt] = __builtin_amdgcn_mfma_f32_16x16x32_bf16(da[mt], bb[3][nt], acc[mt][nt], 0, 0, 0);
  }

  // ---- epilogue: relu(h+b1) dot W2 over this wave's 64 cols ----
  float p[4][4];
  #pragma unroll
  for (int mt = 0; mt < 4; ++mt)
    #pragma unroll
    for (int j = 0; j < 4; ++j) p[mt][j] = 0.f;

  #pragma unroll
  for (int nt = 0; nt < 4; ++nt){
    int col = wn * 64 + nt * 16 + l15;
    float b1c = b1[col], w2c = w2[col];
    #pragma unroll
    for (int mt = 0; mt < 4; ++mt)
      #pragma unroll
      for (int j = 0; j < 4; ++j){
        float v = acc[mt][nt][j] + b1c;
        p[mt][j] += fmaxf(v, 0.f) * w2c;
      }
  }
  #pragma unroll
  for (int mask = 1; mask < 16; mask <<= 1)
    #pragma unroll
    for (int mt = 0; mt < 4; ++mt)
      #pragma unroll
      for (int j = 0; j < 4; ++j)
        p[mt][j] += __shfl_xor(p[mt][j], mask);

  if (l15 == 0){
    #pragma unroll
    for (int mt = 0; mt < 4; ++mt)
      #pragma unroll
      for (int j = 0; j < 4; ++j)
        lpart[wn][wm * 64 + mt * 16 + lg * 4 + j] = p[mt][j];
  }
  __syncthreads();
  if (tid < 128 && e0 + tid < (long)E)
    logits[e0 + tid] = lpart[0][tid] + lpart[1][tid] + lpart[2][tid] + lpart[3][tid] + b2[0];
}

// ---------- per-case softmax + final weighted aggregation: 1 wave per case ----------
__global__ __launch_bounds__(64) void finalize(
    const float* __restrict__ er, const float* __restrict__ ew,
    const float* __restrict__ logits, const int* __restrict__ elist,
    const int* __restrict__ offs, const float* __restrict__ cdeg,
    float* __restrict__ out)
{
  int c = blockIdx.x, lane = threadIdx.x;
  int s = offs[c], e = offs[c + 1];
  int n = e - s;
  if (n == 0){
    *(f32x4*)&out[(size_t)c * H + lane * 4] = (f32x4){0.f,0.f,0.f,0.f};
    return;
  }

  float m = -INFINITY;
  for (int i = lane; i < n; i += 64) m = fmaxf(m, logits[elist[s + i]]);
  #pragma unroll
  for (int mask = 32; mask > 0; mask >>= 1) m = fmaxf(m, __shfl_xor(m, mask));

  float sm = 0.f;
  for (int i = lane; i < n; i += 64) sm += expf(logits[elist[s + i]] - m);
  #pragma unroll
  for (int mask = 32; mask > 0; mask >>= 1) sm += __shfl_xor(sm, mask);

  float gsum = sm + 1e-8f;
  float degc = cdeg[c] + 1e-8f;

  __shared__ float fa[256];
  f32x4 acc = (f32x4){0.f,0.f,0.f,0.f};
  for (int base = 0; base < n; base += 256){
    int chunk = min(n - base, 256);
    for (int i = lane; i < chunk; i += 64){
      int ed = elist[s + base + i];
      fa[i] = 0.8f * expf(logits[ed] - m) / gsum + 0.2f * ew[ed] / degc;
    }
    __syncthreads();
    for (int i = 0; i < chunk; ++i){
      int ed = elist[s + base + i];
      acc += fa[i] * (*(const f32x4*)&er[(size_t)ed * H + lane * 4]);
    }
    __syncthreads();
  }
  *(f32x4*)&out[(size_t)c * H + lane * 4] = acc;
}

extern "C" void kernel_launch(void* const* d_in, const int* in_sizes, int n_in,
                              void* d_out, int out_size, void* d_ws, size_t ws_size,
                              hipStream_t stream){
  const float* er  = (const float*)d_in[0];
  const float* ew  = (const float*)d_in[1];
  const int*   cid = (const int*)d_in[2];
  const float* W1  = (const float*)d_in[4];
  const float* b1  = (const float*)d_in[5];
  const float* W2  = (const float*)d_in[6];
  const float* b2  = (const float*)d_in[7];
  float* out = (float*)d_out;

  int E  = in_sizes[1];
  int NC = out_size / H;

  char* ws = (char*)d_ws;
  auto al = [](size_t x){ return (x + 255) & ~(size_t)255; };
  size_t o = 0;
  int* counts = (int*)(ws + o);  o = al(o + (size_t)NC * 4);
  int* cursor = (int*)(ws + o);  o = al(o + (size_t)NC * 4);
  int* offs   = (int*)(ws + o);  o = al(o + (size_t)(NC + 1) * 4);
  int* elist  = (int*)(ws + o);  o = al(o + (size_t)E * 4);
  float* cdeg = (float*)(ws + o); o = al(o + (size_t)NC * 4);
  float* csum = (float*)(ws + o); o = al(o + (size_t)NC * H * 4);
  float* logits = (float*)(ws + o); o = al(o + (size_t)E * 4);
  unsigned short* w1t2 = (unsigned short*)(ws + o); o = al(o + (size_t)1024 * H * 2);

  hipMemsetAsync(counts, 0, (size_t)NC * 4, stream);
  hipMemsetAsync(cursor, 0, (size_t)NC * 4, stream);

  count_kernel<<<(E + 255) / 256, 256, 0, stream>>>(cid, counts, E);
  scan_offsets<<<1, 1024, 0, stream>>>(counts, offs, NC);
  fill_kernel<<<(E + 255) / 256, 256, 0, stream>>>(cid, cursor, offs, elist, E);
  sort_lists<<<(NC + 255) / 256, 256, 0, stream>>>(elist, offs, NC);
  w1_convert<<<(1024 * H) / 256, 256, 0, stream>>>(W1, w1t2);
  case_sums<<<NC, 64, 0, stream>>>(er, ew, elist, offs, csum, cdeg);
  fused_mlp<<<(E + 127) / 128, 512, 0, stream>>>(er, ew, cid, cdeg, csum, w1t2, b1, W2, b2, logits, E);
  finalize<<<NC, 64, 0, stream>>>(er, ew, logits, elist, offs, cdeg, out);
}